// Round 1
// baseline (1185.234 us; speedup 1.0000x reference)
//
#include <hip/hip_runtime.h>

// Problem constants (fixed by reference)
constexpr int N    = 50000;
constexpr int E    = 800000;
constexpr int FIN  = 128;   // input features
constexpr int HID  = 160;
constexpr int OUTC = 128;
constexpr int NG   = 64;    // graphs
constexpr int ODIM = 10;
constexpr int GP_BLOCKS = 256;  // partial blocks for Z^T X

// ---------- graph preprocessing ----------

__global__ void k_init_deg(float* degF) {
    int i = blockIdx.x * 256 + threadIdx.x;
    if (i < N) degF[i] = 1.0f;   // self loop
}

__global__ void k_edge_count(const int* __restrict__ ei, float* degF, int* cnt) {
    int e = blockIdx.x * 256 + threadIdx.x;
    if (e < E) {
        int s = ei[e];       // row 0: src
        int d = ei[E + e];   // row 1: dst
        atomicAdd(&degF[d], 1.0f);  // in-degree at dst (matches reference gcn_norm)
        atomicAdd(&cnt[s], 1);      // out-degree for CSR-by-src (P^T gather)
    }
}

__global__ void k_dinv(const float* __restrict__ degF, float* dinv) {
    int i = blockIdx.x * 256 + threadIdx.x;
    if (i < N) dinv[i] = rsqrtf(degF[i]);   // deg >= 1 always (self loop)
}

// single-block exclusive scan over N counts -> offsets (off[N] = E)
__global__ void k_scan(const int* __restrict__ cnt, int* __restrict__ off) {
    __shared__ int buf[1024];
    int running = 0;  // uniform across threads
    for (int base = 0; base < N; base += 1024) {
        int i = base + threadIdx.x;
        int v = (i < N) ? cnt[i] : 0;
        buf[threadIdx.x] = v;
        __syncthreads();
        for (int s = 1; s < 1024; s <<= 1) {
            int add = (threadIdx.x >= s) ? buf[threadIdx.x - s] : 0;
            __syncthreads();
            buf[threadIdx.x] += add;
            __syncthreads();
        }
        if (i < N) off[i] = running + buf[threadIdx.x] - v;  // exclusive
        running += buf[1023];
        __syncthreads();
    }
    if (threadIdx.x == 0) off[N] = running;
}

__global__ void k_csr_fill(const int* __restrict__ ei, const float* __restrict__ dinv,
                           const int* __restrict__ off, int* cur,
                           int* csr_dst, float* csr_w) {
    int e = blockIdx.x * 256 + threadIdx.x;
    if (e < E) {
        int s = ei[e];
        int d = ei[E + e];
        int pos = atomicAdd(&cur[s], 1);
        int idx = off[s] + pos;          // slot order within bucket irrelevant (sum)
        csr_dst[idx] = d;
        csr_w[idx]   = dinv[s] * dinv[d];
    }
}

// ---------- pooling indicator init ----------

__global__ void k_cntg(const int* __restrict__ batch, int* cntg) {
    __shared__ int h[NG];
    if (threadIdx.x < NG) h[threadIdx.x] = 0;
    __syncthreads();
    int i = blockIdx.x * 256 + threadIdx.x;
    if (i < N) atomicAdd(&h[batch[i]], 1);
    __syncthreads();
    if (threadIdx.x < NG && h[threadIdx.x]) atomicAdd(&cntg[threadIdx.x], h[threadIdx.x]);
}

__global__ void k_z0(const int* __restrict__ batch, const int* __restrict__ cntg, float* Z0) {
    int i = blockIdx.x * 256 + threadIdx.x;
    if (i < N) {
        int g = batch[i];
        int c = cntg[g]; if (c < 1) c = 1;           // mirrors maximum(counts,1)
        Z0[(size_t)i * 64 + g] = 1.0f / (float)c;    // M^T row
    }
}

// ---------- the hot kernel: one hop of P^T on N x 64 ----------
// out[s] = dinv[s]^2 * in[s] + sum over out-edges (s->d): dinv[s]dinv[d] * in[d]
__global__ __launch_bounds__(256) void k_prop(
        const float* __restrict__ zin, float* __restrict__ zout,
        const int* __restrict__ off, const int* __restrict__ csr_dst,
        const float* __restrict__ csr_w, const float* __restrict__ dinv) {
    int t = blockIdx.x * 256 + threadIdx.x;   // N*16 threads, float4 each
    if (t >= N * 16) return;
    int node = t >> 4;
    int c    = t & 15;
    const float4* z4 = (const float4*)zin;
    float di = dinv[node];
    float4 v = z4[(size_t)node * 16 + c];
    float ws = di * di;
    float ax = ws * v.x, ay = ws * v.y, az = ws * v.z, aw = ws * v.w;
    int e0 = off[node], e1 = off[node + 1];
    for (int e = e0; e < e1; ++e) {
        int d   = csr_dst[e];
        float w = csr_w[e];
        float4 zv = z4[(size_t)d * 16 + c];
        ax += w * zv.x; ay += w * zv.y; az += w * zv.z; aw += w * zv.w;
    }
    ((float4*)zout)[(size_t)node * 16 + c] = make_float4(ax, ay, az, aw);
}

// column sums of Z (N x 64) -> s[g]  (gives M P^k 1)
__global__ void k_colsum(const float* __restrict__ Z, float* s) {
    __shared__ float red[256];
    int g = threadIdx.x & 63, sub = threadIdx.x >> 6;
    float acc = 0.f;
    for (int i = blockIdx.x * 4 + sub; i < N; i += gridDim.x * 4)
        acc += Z[(size_t)i * 64 + g];
    red[threadIdx.x] = acc;
    __syncthreads();
    if (sub == 0)
        atomicAdd(&s[g], red[g] + red[64 + g] + red[128 + g] + red[192 + g]);
}

// partial G = Z15^T X : each block accumulates outer products over a node range
__global__ __launch_bounds__(256) void k_gpart(
        const float* __restrict__ Z, const float* __restrict__ X, float* part) {
    __shared__ float zr[4][64];
    __shared__ float xr[4][128];
    int tid = threadIdx.x;
    int g  = tid >> 2;          // 0..63
    int fb = (tid & 3) * 32;    // 0,32,64,96
    float acc[32];
    #pragma unroll
    for (int j = 0; j < 32; ++j) acc[j] = 0.f;
    int per = (N + gridDim.x - 1) / gridDim.x;
    int n0 = blockIdx.x * per;
    int n1 = n0 + per; if (n1 > N) n1 = N;
    for (int nb = n0; nb < n1; nb += 4) {
        __syncthreads();
        for (int l = tid; l < 768; l += 256) {
            if (l < 256) {
                int nn = l >> 6, ff = l & 63;
                int node = nb + nn;
                zr[nn][ff] = (node < n1) ? Z[(size_t)node * 64 + ff] : 0.f;
            } else {
                int l2 = l - 256;
                int nn = l2 >> 7, ff = l2 & 127;
                int node = nb + nn;
                xr[nn][ff] = (node < n1) ? X[(size_t)node * 128 + ff] : 0.f;
            }
        }
        __syncthreads();
        #pragma unroll
        for (int nn = 0; nn < 4; ++nn) {
            float zv = zr[nn][g];
            #pragma unroll
            for (int j = 0; j < 32; ++j) acc[j] += zv * xr[nn][fb + j];
        }
    }
    float* dst = part + (size_t)blockIdx.x * 8192 + g * 128 + fb;
    #pragma unroll
    for (int j = 0; j < 32; ++j) dst[j] = acc[j];
}

__global__ void k_greduce(const float* __restrict__ part, float* G) {
    int i = blockIdx.x * 256 + threadIdx.x;  // 8192
    float a = 0.f;
    for (int b = 0; b < GP_BLOCKS; ++b) a += part[(size_t)b * 8192 + i];
    G[i] = a;
}

// small dense matmul: C[M,Nn] = A[M,K] @ B[K,Nn]
__global__ void k_smm(const float* __restrict__ A, const float* __restrict__ B,
                      float* C, int M, int K, int Nn) {
    int t = blockIdx.x * 256 + threadIdx.x;
    if (t >= M * Nn) return;
    int m = t / Nn, c = t - m * Nn;
    float a = 0.f;
    for (int k = 0; k < K; ++k) a += A[m * K + k] * B[k * Nn + c];
    C[t] = a;
}

// pooled[g,f] = G[g,:]@Wc[:,f] + s10[g]*c1[f] + s5[g]*c2[f] + b3[f]
__global__ void k_pooled(const float* __restrict__ G, const float* __restrict__ Wc,
                         const float* __restrict__ c1, const float* __restrict__ c2,
                         const float* __restrict__ b3, const float* __restrict__ svec,
                         float* pooled) {
    int t = blockIdx.x * 256 + threadIdx.x;   // 64*128
    if (t >= NG * OUTC) return;
    int g = t >> 7, f = t & 127;
    float a = b3[f] + svec[64 + g] * c1[f] + svec[g] * c2[f];
    for (int k = 0; k < 128; ++k) a += G[g * 128 + k] * Wc[k * 128 + f];
    pooled[t] = a;
}

// logits + log_softmax, one block per graph
__global__ void k_head(const float* __restrict__ pooled, const float* __restrict__ fcw,
                       const float* __restrict__ fcb, float* out) {
    __shared__ float lg[ODIM];
    int g = blockIdx.x, tid = threadIdx.x;
    if (tid < ODIM) {
        float a = fcb[tid];
        for (int k = 0; k < 128; ++k) a += pooled[g * 128 + k] * fcw[k * ODIM + tid];
        lg[tid] = a;
    }
    __syncthreads();
    if (tid == 0) {
        float mx = lg[0];
        for (int j = 1; j < ODIM; ++j) mx = fmaxf(mx, lg[j]);
        float sum = 0.f;
        for (int j = 0; j < ODIM; ++j) sum += expf(lg[j] - mx);
        float lse = mx + logf(sum);
        for (int j = 0; j < ODIM; ++j) out[g * ODIM + j] = lg[j] - lse;
    }
}

extern "C" void kernel_launch(void* const* d_in, const int* in_sizes, int n_in,
                              void* d_out, int out_size, void* d_ws, size_t ws_size,
                              hipStream_t stream) {
    const float* x    = (const float*)d_in[0];
    const int*   ei   = (const int*)d_in[1];
    const int*   batch= (const int*)d_in[2];
    const float* W1   = (const float*)d_in[3];
    const float* b1   = (const float*)d_in[4];
    const float* W2   = (const float*)d_in[5];
    const float* b2   = (const float*)d_in[6];
    const float* W3   = (const float*)d_in[7];
    const float* b3   = (const float*)d_in[8];
    const float* fcw  = (const float*)d_in[9];
    const float* fcb  = (const float*)d_in[10];
    float* out = (float*)d_out;

    char* p = (char*)d_ws;
    auto alloc = [&](size_t bytes) -> void* {
        void* r = (void*)p;
        p += (bytes + 255) & ~(size_t)255;
        return r;
    };
    float* degF    = (float*)alloc((size_t)N * 4);
    float* dinv    = (float*)alloc((size_t)N * 4);
    int*   cnt     = (int*)  alloc((size_t)N * 4);
    int*   off     = (int*)  alloc((size_t)(N + 1) * 4);
    int*   cur     = (int*)  alloc((size_t)N * 4);
    int*   csr_dst = (int*)  alloc((size_t)E * 4);
    float* csr_w   = (float*)alloc((size_t)E * 4);
    int*   cntg    = (int*)  alloc((size_t)NG * 4);
    float* svec    = (float*)alloc(128 * 4);          // s5 [0..63], s10 [64..127]
    float* Z0      = (float*)alloc((size_t)N * 64 * 4);
    float* Z1      = (float*)alloc((size_t)N * 64 * 4);
    float* part    = (float*)alloc((size_t)GP_BLOCKS * 8192 * 4);
    float* G       = (float*)alloc(8192 * 4);
    float* T1      = (float*)alloc(128 * 160 * 4);
    float* Wc      = (float*)alloc(128 * 128 * 4);
    float* c1a     = (float*)alloc(160 * 4);
    float* c1      = (float*)alloc(128 * 4);
    float* c2      = (float*)alloc(128 * 4);
    float* pooled  = (float*)alloc(64 * 128 * 4);

    hipMemsetAsync(cnt,  0, (size_t)N * 4, stream);
    hipMemsetAsync(cur,  0, (size_t)N * 4, stream);
    hipMemsetAsync(cntg, 0, (size_t)NG * 4, stream);
    hipMemsetAsync(svec, 0, 128 * 4, stream);
    hipMemsetAsync(Z0,   0, (size_t)N * 64 * 4, stream);

    int nb_n = (N + 255) / 256;
    int nb_e = (E + 255) / 256;
    k_init_deg<<<nb_n, 256, 0, stream>>>(degF);
    k_edge_count<<<nb_e, 256, 0, stream>>>(ei, degF, cnt);
    k_dinv<<<nb_n, 256, 0, stream>>>(degF, dinv);
    k_scan<<<1, 1024, 0, stream>>>(cnt, off);
    k_csr_fill<<<nb_e, 256, 0, stream>>>(ei, dinv, off, cur, csr_dst, csr_w);
    k_cntg<<<nb_n, 256, 0, stream>>>(batch, cntg);
    k_z0<<<nb_n, 256, 0, stream>>>(batch, cntg, Z0);

    float* zc = Z0;
    float* zn = Z1;
    for (int hop = 1; hop <= 15; ++hop) {
        k_prop<<<(N * 16 + 255) / 256, 256, 0, stream>>>(zc, zn, off, csr_dst, csr_w, dinv);
        float* t = zc; zc = zn; zn = t;
        if (hop == 5)  k_colsum<<<128, 256, 0, stream>>>(zc, svec);       // s5
        if (hop == 10) k_colsum<<<128, 256, 0, stream>>>(zc, svec + 64);  // s10
    }

    k_gpart<<<GP_BLOCKS, 256, 0, stream>>>(zc, x, part);
    k_greduce<<<32, 256, 0, stream>>>(part, G);

    k_smm<<<(128 * 160 + 255) / 256, 256, 0, stream>>>(W1, W2, T1, 128, 160, 160);
    k_smm<<<(128 * 128 + 255) / 256, 256, 0, stream>>>(T1, W3, Wc, 128, 160, 128);
    k_smm<<<1, 256, 0, stream>>>(b1, W2, c1a, 1, 160, 160);
    k_smm<<<1, 256, 0, stream>>>(c1a, W3, c1, 1, 160, 128);
    k_smm<<<1, 256, 0, stream>>>(b2, W3, c2, 1, 160, 128);

    k_pooled<<<32, 256, 0, stream>>>(G, Wc, c1, c2, b3, svec, pooled);
    k_head<<<NG, 64, 0, stream>>>(pooled, fcw, fcb, out);
}

// Round 2
// 714.855 us; speedup vs baseline: 1.6580x; 1.6580x over previous
//
#include <hip/hip_runtime.h>

constexpr int N    = 50000;
constexpr int E    = 800000;
constexpr int NG   = 64;
constexpr int ODIM = 10;
constexpr int OUTC = 128;
constexpr int GP_BLOCKS = 512;
constexpr int SCAN_B = (N + 255) / 256;   // 196

// ---------- bf16 helpers ----------
__device__ __forceinline__ float bflo(unsigned int u) { return __uint_as_float(u << 16); }
__device__ __forceinline__ float bfhi(unsigned int u) { return __uint_as_float(u & 0xFFFF0000u); }
__device__ __forceinline__ unsigned short f2bf(float f) {
    unsigned int x = __float_as_uint(f);
    unsigned int r = x + 0x7FFFu + ((x >> 16) & 1u);
    return (unsigned short)(r >> 16);
}
__device__ __forceinline__ unsigned int pack2(float a, float b) {
    return (unsigned int)f2bf(a) | ((unsigned int)f2bf(b) << 16);
}

// ---------- graph preprocessing ----------
__global__ void k_init_deg(int* degI) {
    int i = blockIdx.x * 256 + threadIdx.x;
    if (i < N) degI[i] = 1;                      // self loop
}

__global__ void k_edge_count(const int* __restrict__ ei, int* degI, int* cnt) {
    int e = blockIdx.x * 256 + threadIdx.x;
    if (e < E) {
        int s = ei[e];
        int d = ei[E + e];
        atomicAdd(&degI[d], 1);                  // in-degree at dst
        atomicAdd(&cnt[s], 1);                   // out-degree (CSR by src, for P^T)
    }
}

__global__ void k_dinv(const int* __restrict__ degI, float* dinv) {
    int i = blockIdx.x * 256 + threadIdx.x;
    if (i < N) dinv[i] = rsqrtf((float)degI[i]);
}

// 3-phase scan: per-block exclusive scan + block sums
__global__ void k_scan1(const int* __restrict__ cnt, int* __restrict__ off, int* bsum) {
    __shared__ int buf[256];
    int tid = threadIdx.x;
    int i = blockIdx.x * 256 + tid;
    int v = (i < N) ? cnt[i] : 0;
    buf[tid] = v;
    __syncthreads();
    for (int s = 1; s < 256; s <<= 1) {
        int add = (tid >= s) ? buf[tid - s] : 0;
        __syncthreads();
        buf[tid] += add;
        __syncthreads();
    }
    if (i < N) off[i] = buf[tid] - v;            // local exclusive
    if (tid == 255) bsum[blockIdx.x] = buf[255];
}

__global__ void k_scan2(int* bsum, int* off) {   // one block, SCAN_B <= 256
    __shared__ int buf[256];
    int tid = threadIdx.x;
    int v = (tid < SCAN_B) ? bsum[tid] : 0;
    buf[tid] = v;
    __syncthreads();
    for (int s = 1; s < 256; s <<= 1) {
        int add = (tid >= s) ? buf[tid - s] : 0;
        __syncthreads();
        buf[tid] += add;
        __syncthreads();
    }
    if (tid < SCAN_B) bsum[tid] = buf[tid] - v;  // exclusive block bases
    if (tid == 0) off[N] = E;                    // counts sum to E exactly
}

__global__ void k_scan3(int* off, const int* __restrict__ bsum) {
    int i = blockIdx.x * 256 + threadIdx.x;
    if (i < N) off[i] += bsum[blockIdx.x];
}

__global__ void k_csr_fill(const int* __restrict__ ei, const float* __restrict__ dinv,
                           const int* __restrict__ off, int* cur, int2* meta) {
    int e = blockIdx.x * 256 + threadIdx.x;
    if (e < E) {
        int s = ei[e];
        int d = ei[E + e];
        int pos = atomicAdd(&cur[s], 1);
        int2 m;
        m.x = d;
        m.y = __float_as_int(dinv[s] * dinv[d]);
        meta[off[s] + pos] = m;                  // slot order irrelevant (sum)
    }
}

// ---------- pooling indicator ----------
__global__ void k_cntg(const int* __restrict__ batch, int* cntg) {
    __shared__ int h[NG];
    if (threadIdx.x < NG) h[threadIdx.x] = 0;
    __syncthreads();
    int i = blockIdx.x * 256 + threadIdx.x;
    if (i < N) atomicAdd(&h[batch[i]], 1);
    __syncthreads();
    if (threadIdx.x < NG && h[threadIdx.x]) atomicAdd(&cntg[threadIdx.x], h[threadIdx.x]);
}

__global__ void k_z0(const int* __restrict__ batch, const int* __restrict__ cntg,
                     unsigned short* Z0) {       // Z0 pre-zeroed (bf16 0 == 0x0000)
    int i = blockIdx.x * 256 + threadIdx.x;
    if (i < N) {
        int g = batch[i];
        int c = cntg[g]; if (c < 1) c = 1;
        Z0[(size_t)i * 64 + g] = f2bf(1.0f / (float)c);
    }
}

// ---------- hot kernel: one hop of P^T on N x 64 (bf16 storage, fp32 accum) ----------
// out[s] = dinv[s]^2 * in[s] + sum over out-edges (s->d) of w * in[d]
__global__ __launch_bounds__(256) void k_prop(
        const uint4* __restrict__ zin, uint4* __restrict__ zout,
        const int* __restrict__ off, const int2* __restrict__ meta,
        const float* __restrict__ dinv) {
    int t = blockIdx.x * 256 + threadIdx.x;      // N*8 threads; 8 lanes/node, 16B each
    if (t >= N * 8) return;
    int node = t >> 3;
    int c    = t & 7;
    float di = dinv[node];
    float ws = di * di;
    uint4 own = zin[(size_t)node * 8 + c];
    float a0 = ws * bflo(own.x), a1 = ws * bfhi(own.x);
    float a2 = ws * bflo(own.y), a3 = ws * bfhi(own.y);
    float a4 = ws * bflo(own.z), a5 = ws * bfhi(own.z);
    float a6 = ws * bflo(own.w), a7 = ws * bfhi(own.w);
    int e  = off[node];
    int e1 = off[node + 1];
    for (; e + 1 < e1; e += 2) {                 // unroll x2: 2 gathers in flight
        int2 m0 = meta[e];
        int2 m1 = meta[e + 1];
        uint4 g0 = zin[(size_t)m0.x * 8 + c];
        uint4 g1 = zin[(size_t)m1.x * 8 + c];
        float w0 = __int_as_float(m0.y);
        float w1 = __int_as_float(m1.y);
        a0 += w0 * bflo(g0.x); a1 += w0 * bfhi(g0.x);
        a2 += w0 * bflo(g0.y); a3 += w0 * bfhi(g0.y);
        a4 += w0 * bflo(g0.z); a5 += w0 * bfhi(g0.z);
        a6 += w0 * bflo(g0.w); a7 += w0 * bfhi(g0.w);
        a0 += w1 * bflo(g1.x); a1 += w1 * bfhi(g1.x);
        a2 += w1 * bflo(g1.y); a3 += w1 * bfhi(g1.y);
        a4 += w1 * bflo(g1.z); a5 += w1 * bfhi(g1.z);
        a6 += w1 * bflo(g1.w); a7 += w1 * bfhi(g1.w);
    }
    if (e < e1) {
        int2 m0 = meta[e];
        uint4 g0 = zin[(size_t)m0.x * 8 + c];
        float w0 = __int_as_float(m0.y);
        a0 += w0 * bflo(g0.x); a1 += w0 * bfhi(g0.x);
        a2 += w0 * bflo(g0.y); a3 += w0 * bfhi(g0.y);
        a4 += w0 * bflo(g0.z); a5 += w0 * bfhi(g0.z);
        a6 += w0 * bflo(g0.w); a7 += w0 * bfhi(g0.w);
    }
    uint4 o;
    o.x = pack2(a0, a1); o.y = pack2(a2, a3);
    o.z = pack2(a4, a5); o.w = pack2(a6, a7);
    zout[(size_t)node * 8 + c] = o;
}

// column sums of bf16 Z -> s[g]  (M P^k 1)
__global__ void k_colsum(const unsigned short* __restrict__ Z, float* s) {
    __shared__ float red[256];
    int g = threadIdx.x & 63, sub = threadIdx.x >> 6;
    float acc = 0.f;
    for (int i = blockIdx.x * 4 + sub; i < N; i += gridDim.x * 4)
        acc += __uint_as_float(((unsigned int)Z[(size_t)i * 64 + g]) << 16);
    red[threadIdx.x] = acc;
    __syncthreads();
    if (sub == 0)
        atomicAdd(&s[g], red[g] + red[64 + g] + red[128 + g] + red[192 + g]);
}

// partial G = Z15^T X, conflict-free LDS, 8 float4 accs/thread
__global__ __launch_bounds__(256) void k_gpart(
        const uint4* __restrict__ Z, const float4* __restrict__ X, float* part) {
    __shared__ unsigned int zr[32][32];          // 32 nodes x 64 bf16
    __shared__ float xr[32][128];                // 32 nodes x 128 fp32
    int tid = threadIdx.x;
    int f4 = tid & 31;                           // float4 index into 128 cols
    int gs = tid >> 5;                           // 0..7 -> g = gs*8 + k
    float4 acc[8];
    #pragma unroll
    for (int k = 0; k < 8; ++k) acc[k] = make_float4(0.f, 0.f, 0.f, 0.f);

    int per = (N + gridDim.x - 1) / gridDim.x;
    int n0 = blockIdx.x * per;
    int n1 = n0 + per; if (n1 > N) n1 = N;

    for (int nb = n0; nb < n1; nb += 32) {
        __syncthreads();
        {   // Z tile: 256 uint4, one per thread
            int nn = tid >> 3, cc = tid & 7;
            int node = nb + nn;
            uint4 zv = make_uint4(0u, 0u, 0u, 0u);
            if (node < n1) zv = Z[(size_t)node * 8 + cc];
            ((uint4*)&zr[nn][0])[cc] = zv;
        }
        #pragma unroll
        for (int r = 0; r < 4; ++r) {            // X tile: 1024 float4, 4 per thread
            int l = r * 256 + tid;
            int nn = l >> 5, c4 = l & 31;
            int node = nb + nn;
            float4 xv = make_float4(0.f, 0.f, 0.f, 0.f);
            if (node < n1) xv = X[(size_t)node * 32 + c4];
            ((float4*)&xr[nn][0])[c4] = xv;
        }
        __syncthreads();
        for (int nn = 0; nn < 32; ++nn) {
            float4 xv = ((const float4*)&xr[nn][0])[f4];
            uint4 zu = ((const uint4*)&zr[nn][0])[gs];   // 8 bf16, wave-broadcast
            float z0 = bflo(zu.x), z1 = bfhi(zu.x);
            float z2 = bflo(zu.y), z3 = bfhi(zu.y);
            float z4 = bflo(zu.z), z5 = bfhi(zu.z);
            float z6 = bflo(zu.w), z7 = bfhi(zu.w);
            acc[0].x += z0*xv.x; acc[0].y += z0*xv.y; acc[0].z += z0*xv.z; acc[0].w += z0*xv.w;
            acc[1].x += z1*xv.x; acc[1].y += z1*xv.y; acc[1].z += z1*xv.z; acc[1].w += z1*xv.w;
            acc[2].x += z2*xv.x; acc[2].y += z2*xv.y; acc[2].z += z2*xv.z; acc[2].w += z2*xv.w;
            acc[3].x += z3*xv.x; acc[3].y += z3*xv.y; acc[3].z += z3*xv.z; acc[3].w += z3*xv.w;
            acc[4].x += z4*xv.x; acc[4].y += z4*xv.y; acc[4].z += z4*xv.z; acc[4].w += z4*xv.w;
            acc[5].x += z5*xv.x; acc[5].y += z5*xv.y; acc[5].z += z5*xv.z; acc[5].w += z5*xv.w;
            acc[6].x += z6*xv.x; acc[6].y += z6*xv.y; acc[6].z += z6*xv.z; acc[6].w += z6*xv.w;
            acc[7].x += z7*xv.x; acc[7].y += z7*xv.y; acc[7].z += z7*xv.z; acc[7].w += z7*xv.w;
        }
    }
    float4* dst = (float4*)(part + (size_t)blockIdx.x * 8192);
    #pragma unroll
    for (int k = 0; k < 8; ++k) dst[(gs * 8 + k) * 32 + f4] = acc[k];
}

__global__ void k_greduce(const float4* __restrict__ part, float4* G) {
    int i = blockIdx.x * 256 + threadIdx.x;      // 2048 float4s
    float4 a = make_float4(0.f, 0.f, 0.f, 0.f);
    for (int b = 0; b < GP_BLOCKS; ++b) {
        float4 v = part[(size_t)b * 2048 + i];
        a.x += v.x; a.y += v.y; a.z += v.z; a.w += v.w;
    }
    G[i] = a;
}

// small dense matmul C[M,Nn] = A[M,K] @ B[K,Nn]
__global__ void k_smm(const float* __restrict__ A, const float* __restrict__ B,
                      float* C, int M, int K, int Nn) {
    int t = blockIdx.x * 256 + threadIdx.x;
    if (t >= M * Nn) return;
    int m = t / Nn, c = t - m * Nn;
    float a = 0.f;
    for (int k = 0; k < K; ++k) a += A[m * K + k] * B[k * Nn + c];
    C[t] = a;
}

// pooled[g,f] = G[g,:]@Wc[:,f] + s10[g]*c1[f] + s5[g]*c2[f] + b3[f]
__global__ void k_pooled(const float* __restrict__ G, const float* __restrict__ Wc,
                         const float* __restrict__ c1, const float* __restrict__ c2,
                         const float* __restrict__ b3, const float* __restrict__ svec,
                         float* pooled) {
    int t = blockIdx.x * 256 + threadIdx.x;
    if (t >= NG * OUTC) return;
    int g = t >> 7, f = t & 127;
    float a = b3[f] + svec[64 + g] * c1[f] + svec[g] * c2[f];
    for (int k = 0; k < 128; ++k) a += G[g * 128 + k] * Wc[k * 128 + f];
    pooled[t] = a;
}

__global__ void k_head(const float* __restrict__ pooled, const float* __restrict__ fcw,
                       const float* __restrict__ fcb, float* out) {
    __shared__ float lg[ODIM];
    int g = blockIdx.x, tid = threadIdx.x;
    if (tid < ODIM) {
        float a = fcb[tid];
        for (int k = 0; k < 128; ++k) a += pooled[g * 128 + k] * fcw[k * ODIM + tid];
        lg[tid] = a;
    }
    __syncthreads();
    if (tid == 0) {
        float mx = lg[0];
        for (int j = 1; j < ODIM; ++j) mx = fmaxf(mx, lg[j]);
        float sum = 0.f;
        for (int j = 0; j < ODIM; ++j) sum += expf(lg[j] - mx);
        float lse = mx + logf(sum);
        for (int j = 0; j < ODIM; ++j) out[g * ODIM + j] = lg[j] - lse;
    }
}

extern "C" void kernel_launch(void* const* d_in, const int* in_sizes, int n_in,
                              void* d_out, int out_size, void* d_ws, size_t ws_size,
                              hipStream_t stream) {
    const float* x    = (const float*)d_in[0];
    const int*   ei   = (const int*)d_in[1];
    const int*   batch= (const int*)d_in[2];
    const float* W1   = (const float*)d_in[3];
    const float* b1   = (const float*)d_in[4];
    const float* W2   = (const float*)d_in[5];
    const float* b2   = (const float*)d_in[6];
    const float* W3   = (const float*)d_in[7];
    const float* b3   = (const float*)d_in[8];
    const float* fcw  = (const float*)d_in[9];
    const float* fcb  = (const float*)d_in[10];
    float* out = (float*)d_out;

    char* p = (char*)d_ws;
    auto alloc = [&](size_t bytes) -> void* {
        void* r = (void*)p;
        p += (bytes + 255) & ~(size_t)255;
        return r;
    };
    int*   degI    = (int*)  alloc((size_t)N * 4);
    float* dinv    = (float*)alloc((size_t)N * 4);
    int*   cnt     = (int*)  alloc((size_t)N * 4);
    int*   off     = (int*)  alloc((size_t)(N + 1) * 4);
    int*   cur     = (int*)  alloc((size_t)N * 4);
    int*   bsum    = (int*)  alloc((size_t)SCAN_B * 4);
    int2*  meta    = (int2*) alloc((size_t)E * 8);
    int*   cntg    = (int*)  alloc((size_t)NG * 4);
    float* svec    = (float*)alloc(128 * 4);                   // s5 | s10
    unsigned short* Z0 = (unsigned short*)alloc((size_t)N * 64 * 2);
    unsigned short* Z1 = (unsigned short*)alloc((size_t)N * 64 * 2);
    float* part    = (float*)alloc((size_t)GP_BLOCKS * 8192 * 4);
    float* G       = (float*)alloc(8192 * 4);
    float* T1      = (float*)alloc(128 * 160 * 4);
    float* Wc      = (float*)alloc(128 * 128 * 4);
    float* c1a     = (float*)alloc(160 * 4);
    float* c1      = (float*)alloc(128 * 4);
    float* c2      = (float*)alloc(128 * 4);
    float* pooled  = (float*)alloc(64 * 128 * 4);

    hipMemsetAsync(cnt,  0, (size_t)N * 4, stream);
    hipMemsetAsync(cur,  0, (size_t)N * 4, stream);
    hipMemsetAsync(cntg, 0, (size_t)NG * 4, stream);
    hipMemsetAsync(svec, 0, 128 * 4, stream);
    hipMemsetAsync(Z0,   0, (size_t)N * 64 * 2, stream);

    int nb_n = (N + 255) / 256;
    int nb_e = (E + 255) / 256;
    k_init_deg<<<nb_n, 256, 0, stream>>>(degI);
    k_edge_count<<<nb_e, 256, 0, stream>>>(ei, degI, cnt);
    k_dinv<<<nb_n, 256, 0, stream>>>(degI, dinv);
    k_scan1<<<SCAN_B, 256, 0, stream>>>(cnt, off, bsum);
    k_scan2<<<1, 256, 0, stream>>>(bsum, off);
    k_scan3<<<SCAN_B, 256, 0, stream>>>(off, bsum);
    k_csr_fill<<<nb_e, 256, 0, stream>>>(ei, dinv, off, cur, meta);
    k_cntg<<<nb_n, 256, 0, stream>>>(batch, cntg);
    k_z0<<<nb_n, 256, 0, stream>>>(batch, cntg, Z0);

    unsigned short* zc = Z0;
    unsigned short* zn = Z1;
    for (int hop = 1; hop <= 15; ++hop) {
        k_prop<<<(N * 8 + 255) / 256, 256, 0, stream>>>(
            (const uint4*)zc, (uint4*)zn, off, meta, dinv);
        unsigned short* t = zc; zc = zn; zn = t;
        if (hop == 5)  k_colsum<<<128, 256, 0, stream>>>(zc, svec);
        if (hop == 10) k_colsum<<<128, 256, 0, stream>>>(zc, svec + 64);
    }

    k_gpart<<<GP_BLOCKS, 256, 0, stream>>>((const uint4*)zc, (const float4*)x, part);
    k_greduce<<<8, 256, 0, stream>>>((const float4*)part, (float4*)G);

    k_smm<<<(128 * 160 + 255) / 256, 256, 0, stream>>>(W1, W2, T1, 128, 160, 160);
    k_smm<<<(128 * 128 + 255) / 256, 256, 0, stream>>>(T1, W3, Wc, 128, 160, 128);
    k_smm<<<1, 256, 0, stream>>>(b1, W2, c1a, 1, 160, 160);
    k_smm<<<1, 256, 0, stream>>>(c1a, W3, c1, 1, 160, 128);
    k_smm<<<1, 256, 0, stream>>>(b2, W3, c2, 1, 160, 128);

    k_pooled<<<32, 256, 0, stream>>>(G, Wc, c1, c2, b3, svec, pooled);
    k_head<<<NG, 64, 0, stream>>>(pooled, fcw, fcb, out);
}

// Round 4
// 708.135 us; speedup vs baseline: 1.6737x; 1.0095x over previous
//
#include <hip/hip_runtime.h>

constexpr int N    = 50000;
constexpr int E    = 800000;
constexpr int NG   = 64;
constexpr int ODIM = 10;
constexpr int OUTC = 128;
constexpr int GP_BLOCKS = 256;
constexpr int SCAN_B = (N + 255) / 256;   // 196
constexpr float SCALE  = 8192.0f;         // 2^13: centers Z in e4m3 normal range
constexpr float INVSCALE = 1.0f / 8192.0f;

typedef float floatx2 __attribute__((ext_vector_type(2)));

// ---------- fp8 e4m3 helpers ----------
__device__ __forceinline__ void unp4(unsigned int u, float* f) {
    floatx2 lo = __builtin_amdgcn_cvt_pk_f32_fp8(u, false);
    floatx2 hi = __builtin_amdgcn_cvt_pk_f32_fp8(u, true);
    f[0] = lo.x; f[1] = lo.y; f[2] = hi.x; f[3] = hi.y;
}
__device__ __forceinline__ unsigned int pk4(float a, float b, float c, float d) {
    int r = __builtin_amdgcn_cvt_pk_fp8_f32(a, b, 0, false);
    r = __builtin_amdgcn_cvt_pk_fp8_f32(c, d, r, true);
    return (unsigned int)r;
}

// ---------- graph preprocessing ----------
__global__ void k_init_deg(int* degI) {
    int i = blockIdx.x * 256 + threadIdx.x;
    if (i < N) degI[i] = 1;                      // self loop
}

// counts + slot assignment in one pass (pos_e removes atomics from csr_fill)
__global__ void k_edge_count(const int* __restrict__ ei, int* degI, int* cnt,
                             int* __restrict__ pos_e) {
    int e = blockIdx.x * 256 + threadIdx.x;
    if (e < E) {
        int s = ei[e];
        int d = ei[E + e];
        atomicAdd(&degI[d], 1);                  // in-degree at dst
        pos_e[e] = atomicAdd(&cnt[s], 1);        // out-degree + slot
    }
}

__global__ void k_dinv(const int* __restrict__ degI, float* dinv) {
    int i = blockIdx.x * 256 + threadIdx.x;
    if (i < N) dinv[i] = rsqrtf((float)degI[i]);
}

__global__ void k_scan1(const int* __restrict__ cnt, int* __restrict__ off, int* bsum) {
    __shared__ int buf[256];
    int tid = threadIdx.x;
    int i = blockIdx.x * 256 + tid;
    int v = (i < N) ? cnt[i] : 0;
    buf[tid] = v;
    __syncthreads();
    for (int s = 1; s < 256; s <<= 1) {
        int add = (tid >= s) ? buf[tid - s] : 0;
        __syncthreads();
        buf[tid] += add;
        __syncthreads();
    }
    if (i < N) off[i] = buf[tid] - v;
    if (tid == 255) bsum[blockIdx.x] = buf[255];
}

__global__ void k_scan2(int* bsum, int* off) {
    __shared__ int buf[256];
    int tid = threadIdx.x;
    int v = (tid < SCAN_B) ? bsum[tid] : 0;
    buf[tid] = v;
    __syncthreads();
    for (int s = 1; s < 256; s <<= 1) {
        int add = (tid >= s) ? buf[tid - s] : 0;
        __syncthreads();
        buf[tid] += add;
        __syncthreads();
    }
    if (tid < SCAN_B) bsum[tid] = buf[tid] - v;
    if (tid == 0) off[N] = E;
}

__global__ void k_scan3(int* off, const int* __restrict__ bsum) {
    int i = blockIdx.x * 256 + threadIdx.x;
    if (i < N) off[i] += bsum[blockIdx.x];
}

// no atomics: slot comes from pos_e
__global__ void k_csr_fill(const int* __restrict__ ei, const float* __restrict__ dinv,
                           const int* __restrict__ off, const int* __restrict__ pos_e,
                           unsigned long long* __restrict__ meta) {
    int e = blockIdx.x * 256 + threadIdx.x;
    if (e < E) {
        int s = ei[e];
        int d = ei[E + e];
        unsigned long long m =
            ((unsigned long long)__float_as_uint(dinv[s] * dinv[d]) << 32) |
            (unsigned int)d;
        meta[off[s] + pos_e[e]] = m;
    }
}

// ---------- pooling indicator ----------
__global__ void k_cntg(const int* __restrict__ batch, int* cntg) {
    __shared__ int h[NG];
    if (threadIdx.x < NG) h[threadIdx.x] = 0;
    __syncthreads();
    int i = blockIdx.x * 256 + threadIdx.x;
    if (i < N) atomicAdd(&h[batch[i]], 1);
    __syncthreads();
    if (threadIdx.x < NG && h[threadIdx.x]) atomicAdd(&cntg[threadIdx.x], h[threadIdx.x]);
}

__global__ void k_z0(const int* __restrict__ batch, const int* __restrict__ cntg,
                     unsigned char* Z0) {        // fp8, pre-zeroed
    int i = blockIdx.x * 256 + threadIdx.x;
    if (i < N) {
        int g = batch[i];
        int c = cntg[g]; if (c < 1) c = 1;
        float v = SCALE / (float)c;
        Z0[(size_t)i * 64 + g] =
            (unsigned char)(__builtin_amdgcn_cvt_pk_fp8_f32(v, v, 0, false) & 0xFF);
    }
}

// ---------- hot kernel: one hop of P^T on N x 64 fp8 (fp32 accum) ----------
__device__ __forceinline__ void fma16(float* acc, uint4 g, float w) {
    float f[16];
    unp4(g.x, f); unp4(g.y, f + 4); unp4(g.z, f + 8); unp4(g.w, f + 12);
    #pragma unroll
    for (int k = 0; k < 16; ++k) acc[k] += w * f[k];
}

__global__ __launch_bounds__(256) void k_prop(
        const uint4* __restrict__ zin, uint4* __restrict__ zout,
        const int* __restrict__ off, const unsigned long long* __restrict__ meta,
        const float* __restrict__ dinv) {
    int t = blockIdx.x * 256 + threadIdx.x;      // N*4 threads; 4 lanes/node, 16B each
    if (t >= N * 4) return;
    int node = t >> 2;
    int c    = t & 3;
    float di = dinv[node];
    float ws = di * di;
    uint4 own = zin[(size_t)node * 4 + c];
    float acc[16];
    {
        float f[16];
        unp4(own.x, f); unp4(own.y, f + 4); unp4(own.z, f + 8); unp4(own.w, f + 12);
        #pragma unroll
        for (int k = 0; k < 16; ++k) acc[k] = ws * f[k];
    }
    int e  = off[node];
    int e1 = off[node + 1];
    for (; e + 3 < e1; e += 4) {                 // 4 gathers in flight
        unsigned long long m0 = __builtin_nontemporal_load(meta + e);
        unsigned long long m1 = __builtin_nontemporal_load(meta + e + 1);
        unsigned long long m2 = __builtin_nontemporal_load(meta + e + 2);
        unsigned long long m3 = __builtin_nontemporal_load(meta + e + 3);
        uint4 g0 = zin[(size_t)(unsigned int)m0 * 4 + c];
        uint4 g1 = zin[(size_t)(unsigned int)m1 * 4 + c];
        uint4 g2 = zin[(size_t)(unsigned int)m2 * 4 + c];
        uint4 g3 = zin[(size_t)(unsigned int)m3 * 4 + c];
        fma16(acc, g0, __uint_as_float((unsigned int)(m0 >> 32)));
        fma16(acc, g1, __uint_as_float((unsigned int)(m1 >> 32)));
        fma16(acc, g2, __uint_as_float((unsigned int)(m2 >> 32)));
        fma16(acc, g3, __uint_as_float((unsigned int)(m3 >> 32)));
    }
    for (; e < e1; ++e) {
        unsigned long long m0 = __builtin_nontemporal_load(meta + e);
        uint4 g0 = zin[(size_t)(unsigned int)m0 * 4 + c];
        fma16(acc, g0, __uint_as_float((unsigned int)(m0 >> 32)));
    }
    uint4 o;
    o.x = pk4(acc[0],  acc[1],  acc[2],  acc[3]);
    o.y = pk4(acc[4],  acc[5],  acc[6],  acc[7]);
    o.z = pk4(acc[8],  acc[9],  acc[10], acc[11]);
    o.w = pk4(acc[12], acc[13], acc[14], acc[15]);
    zout[(size_t)node * 4 + c] = o;   // keep in L2: next hop gathers from this buffer
}

// column sums of fp8 Z -> s[g] * invS
__global__ void k_colsum(const unsigned int* __restrict__ Z, float* s) {
    __shared__ float red[256];
    int g = threadIdx.x & 63, sub = threadIdx.x >> 6;
    int w = g >> 2;
    int word = (g >> 1) & 1;
    int odd  = g & 1;
    float acc = 0.f;
    for (int i = blockIdx.x * 4 + sub; i < N; i += gridDim.x * 4) {
        unsigned int u = Z[(size_t)i * 16 + w];
        floatx2 p = word ? __builtin_amdgcn_cvt_pk_f32_fp8(u, true)
                         : __builtin_amdgcn_cvt_pk_f32_fp8(u, false);
        acc += odd ? p.y : p.x;
    }
    red[threadIdx.x] = acc;
    __syncthreads();
    if (sub == 0)
        atomicAdd(&s[g], (red[g] + red[64 + g] + red[128 + g] + red[192 + g]) * INVSCALE);
}

// partial G = Z15^T X (Z fp8)
__global__ __launch_bounds__(256) void k_gpart(
        const uint4* __restrict__ Z, const float4* __restrict__ X, float* part) {
    __shared__ unsigned int zr[32][16];          // 32 nodes x 64 fp8
    __shared__ float xr[32][128];                // 32 nodes x 128 fp32
    int tid = threadIdx.x;
    int f4 = tid & 31;
    int gs = tid >> 5;                           // 0..7 -> g = gs*8 + k
    float4 acc[8];
    #pragma unroll
    for (int k = 0; k < 8; ++k) acc[k] = make_float4(0.f, 0.f, 0.f, 0.f);

    int per = (N + gridDim.x - 1) / gridDim.x;
    int n0 = blockIdx.x * per;
    int n1 = n0 + per; if (n1 > N) n1 = N;

    for (int nb = n0; nb < n1; nb += 32) {
        __syncthreads();
        if (tid < 128) {                         // Z tile: 128 uint4
            int nn = tid >> 2, q = tid & 3;
            int node = nb + nn;
            uint4 zv = make_uint4(0u, 0u, 0u, 0u);
            if (node < n1) zv = Z[(size_t)node * 4 + q];
            ((uint4*)&zr[nn][0])[q] = zv;
        }
        #pragma unroll
        for (int r = 0; r < 4; ++r) {            // X tile: 1024 float4
            int l = r * 256 + tid;
            int nn = l >> 5, c4 = l & 31;
            int node = nb + nn;
            float4 xv = make_float4(0.f, 0.f, 0.f, 0.f);
            if (node < n1) xv = X[(size_t)node * 32 + c4];
            ((float4*)&xr[nn][0])[c4] = xv;
        }
        __syncthreads();
        for (int nn = 0; nn < 32; ++nn) {
            float4 xv = ((const float4*)&xr[nn][0])[f4];
            unsigned int za = zr[nn][gs * 2], zb = zr[nn][gs * 2 + 1];
            float zf[8];
            unp4(za, zf); unp4(zb, zf + 4);
            #pragma unroll
            for (int k = 0; k < 8; ++k) {
                acc[k].x += zf[k] * xv.x; acc[k].y += zf[k] * xv.y;
                acc[k].z += zf[k] * xv.z; acc[k].w += zf[k] * xv.w;
            }
        }
    }
    float4* dst = (float4*)(part + (size_t)blockIdx.x * 8192);
    #pragma unroll
    for (int k = 0; k < 8; ++k) dst[(gs * 8 + k) * 32 + f4] = acc[k];
}

// two-stage reduce: 128 blocks, block handles 16 float4 outputs
__global__ void k_greduce(const float4* __restrict__ part, float4* G) {
    __shared__ float4 red[256];
    int tid = threadIdx.x;
    int o4 = blockIdx.x * 16 + (tid & 15);       // 0..2047
    int slice = tid >> 4;                        // 0..15, each 16 b's
    float4 a = make_float4(0.f, 0.f, 0.f, 0.f);
    #pragma unroll 4
    for (int k = 0; k < GP_BLOCKS / 16; ++k) {
        float4 v = part[(size_t)(slice * (GP_BLOCKS / 16) + k) * 2048 + o4];
        a.x += v.x; a.y += v.y; a.z += v.z; a.w += v.w;
    }
    red[tid] = a;
    __syncthreads();
    for (int s = 128; s >= 16; s >>= 1) {
        if (tid < s) {
            float4 b = red[tid + s];
            red[tid].x += b.x; red[tid].y += b.y; red[tid].z += b.z; red[tid].w += b.w;
        }
        __syncthreads();
    }
    if (tid < 16) {
        float4 r = red[tid];
        G[o4] = make_float4(r.x * INVSCALE, r.y * INVSCALE, r.z * INVSCALE, r.w * INVSCALE);
    }
}

// small dense matmul C[M,Nn] = A[M,K] @ B[K,Nn]
__global__ void k_smm(const float* __restrict__ A, const float* __restrict__ B,
                      float* C, int M, int K, int Nn) {
    int t = blockIdx.x * 256 + threadIdx.x;
    if (t >= M * Nn) return;
    int m = t / Nn, c = t - m * Nn;
    float a = 0.f;
    for (int k = 0; k < K; ++k) a += A[m * K + k] * B[k * Nn + c];
    C[t] = a;
}

__global__ void k_pooled(const float* __restrict__ G, const float* __restrict__ Wc,
                         const float* __restrict__ c1, const float* __restrict__ c2,
                         const float* __restrict__ b3, const float* __restrict__ svec,
                         float* pooled) {
    int t = blockIdx.x * 256 + threadIdx.x;
    if (t >= NG * OUTC) return;
    int g = t >> 7, f = t & 127;
    float a = b3[f] + svec[64 + g] * c1[f] + svec[g] * c2[f];
    for (int k = 0; k < 128; ++k) a += G[g * 128 + k] * Wc[k * 128 + f];
    pooled[t] = a;
}

__global__ void k_head(const float* __restrict__ pooled, const float* __restrict__ fcw,
                       const float* __restrict__ fcb, float* out) {
    __shared__ float lg[ODIM];
    int g = blockIdx.x, tid = threadIdx.x;
    if (tid < ODIM) {
        float a = fcb[tid];
        for (int k = 0; k < 128; ++k) a += pooled[g * 128 + k] * fcw[k * ODIM + tid];
        lg[tid] = a;
    }
    __syncthreads();
    if (tid == 0) {
        float mx = lg[0];
        for (int j = 1; j < ODIM; ++j) mx = fmaxf(mx, lg[j]);
        float sum = 0.f;
        for (int j = 0; j < ODIM; ++j) sum += expf(lg[j] - mx);
        float lse = mx + logf(sum);
        for (int j = 0; j < ODIM; ++j) out[g * ODIM + j] = lg[j] - lse;
    }
}

extern "C" void kernel_launch(void* const* d_in, const int* in_sizes, int n_in,
                              void* d_out, int out_size, void* d_ws, size_t ws_size,
                              hipStream_t stream) {
    const float* x    = (const float*)d_in[0];
    const int*   ei   = (const int*)d_in[1];
    const int*   batch= (const int*)d_in[2];
    const float* W1   = (const float*)d_in[3];
    const float* b1   = (const float*)d_in[4];
    const float* W2   = (const float*)d_in[5];
    const float* b2   = (const float*)d_in[6];
    const float* W3   = (const float*)d_in[7];
    const float* b3   = (const float*)d_in[8];
    const float* fcw  = (const float*)d_in[9];
    const float* fcb  = (const float*)d_in[10];
    float* out = (float*)d_out;

    char* p = (char*)d_ws;
    auto alloc = [&](size_t bytes) -> void* {
        void* r = (void*)p;
        p += (bytes + 255) & ~(size_t)255;
        return r;
    };
    int*   degI    = (int*)  alloc((size_t)N * 4);
    float* dinv    = (float*)alloc((size_t)N * 4);
    int*   cnt     = (int*)  alloc((size_t)N * 4);
    int*   off     = (int*)  alloc((size_t)(N + 1) * 4);
    int*   bsum    = (int*)  alloc((size_t)SCAN_B * 4);
    int*   pos_e   = (int*)  alloc((size_t)E * 4);
    unsigned long long* meta = (unsigned long long*)alloc((size_t)E * 8);
    int*   cntg    = (int*)  alloc((size_t)NG * 4);
    float* svec    = (float*)alloc(128 * 4);
    unsigned char* Z0 = (unsigned char*)alloc((size_t)N * 64);
    unsigned char* Z1 = (unsigned char*)alloc((size_t)N * 64);
    float* part    = (float*)alloc((size_t)GP_BLOCKS * 8192 * 4);
    float* G       = (float*)alloc(8192 * 4);
    float* T1      = (float*)alloc(128 * 160 * 4);
    float* Wc      = (float*)alloc(128 * 128 * 4);
    float* c1a     = (float*)alloc(160 * 4);
    float* c1      = (float*)alloc(128 * 4);
    float* c2      = (float*)alloc(128 * 4);
    float* pooled  = (float*)alloc(64 * 128 * 4);

    (void)hipMemsetAsync(cnt,  0, (size_t)N * 4, stream);
    (void)hipMemsetAsync(cntg, 0, (size_t)NG * 4, stream);
    (void)hipMemsetAsync(svec, 0, 128 * 4, stream);
    (void)hipMemsetAsync(Z0,   0, (size_t)N * 64, stream);

    int nb_n = (N + 255) / 256;
    int nb_e = (E + 255) / 256;
    k_init_deg<<<nb_n, 256, 0, stream>>>(degI);
    k_edge_count<<<nb_e, 256, 0, stream>>>(ei, degI, cnt, pos_e);
    k_dinv<<<nb_n, 256, 0, stream>>>(degI, dinv);
    k_scan1<<<SCAN_B, 256, 0, stream>>>(cnt, off, bsum);
    k_scan2<<<1, 256, 0, stream>>>(bsum, off);
    k_scan3<<<SCAN_B, 256, 0, stream>>>(off, bsum);
    k_csr_fill<<<nb_e, 256, 0, stream>>>(ei, dinv, off, pos_e, meta);
    k_cntg<<<nb_n, 256, 0, stream>>>(batch, cntg);
    k_z0<<<nb_n, 256, 0, stream>>>(batch, cntg, Z0);

    unsigned char* zc = Z0;
    unsigned char* zn = Z1;
    for (int hop = 1; hop <= 15; ++hop) {
        k_prop<<<(N * 4 + 255) / 256, 256, 0, stream>>>(
            (const uint4*)zc, (uint4*)zn, off, meta, dinv);
        unsigned char* t = zc; zc = zn; zn = t;
        if (hop == 5)  k_colsum<<<128, 256, 0, stream>>>((const unsigned int*)zc, svec);
        if (hop == 10) k_colsum<<<128, 256, 0, stream>>>((const unsigned int*)zc, svec + 64);
    }

    k_gpart<<<GP_BLOCKS, 256, 0, stream>>>((const uint4*)zc, (const float4*)x, part);
    k_greduce<<<128, 256, 0, stream>>>((const float4*)part, (float4*)G);

    k_smm<<<(128 * 160 + 255) / 256, 256, 0, stream>>>(W1, W2, T1, 128, 160, 160);
    k_smm<<<(128 * 128 + 255) / 256, 256, 0, stream>>>(T1, W3, Wc, 128, 160, 128);
    k_smm<<<1, 256, 0, stream>>>(b1, W2, c1a, 1, 160, 160);
    k_smm<<<1, 256, 0, stream>>>(c1a, W3, c1, 1, 160, 128);
    k_smm<<<1, 256, 0, stream>>>(b2, W3, c2, 1, 160, 128);

    k_pooled<<<32, 256, 0, stream>>>(G, Wc, c1, c2, b3, svec, pooled);
    k_head<<<NG, 64, 0, stream>>>(pooled, fcw, fcb, out);
}

// Round 5
// 603.944 us; speedup vs baseline: 1.9625x; 1.1725x over previous
//
#include <hip/hip_runtime.h>

constexpr int N    = 50000;
constexpr int E    = 800000;
constexpr int NG   = 64;
constexpr int ODIM = 10;
constexpr int OUTC = 128;
constexpr int GP_BLOCKS = 256;
constexpr int SCAN_B = (N + 255) / 256;   // 196
constexpr float SCALE  = 8192.0f;         // 2^13: centers Z in e4m3 normal range
constexpr float INVSCALE = 1.0f / 8192.0f;

typedef float floatx2 __attribute__((ext_vector_type(2)));

// ---------- fp8 e4m3 helpers ----------
__device__ __forceinline__ void unp4(unsigned int u, float* f) {
    floatx2 lo = __builtin_amdgcn_cvt_pk_f32_fp8(u, false);
    floatx2 hi = __builtin_amdgcn_cvt_pk_f32_fp8(u, true);
    f[0] = lo.x; f[1] = lo.y; f[2] = hi.x; f[3] = hi.y;
}
__device__ __forceinline__ unsigned int pk4(float a, float b, float c, float d) {
    int r = __builtin_amdgcn_cvt_pk_fp8_f32(a, b, 0, false);
    r = __builtin_amdgcn_cvt_pk_fp8_f32(c, d, r, true);
    return (unsigned int)r;
}

// ---------- init: degI=1, cnt=0, cntg=0, svec=0 in one dispatch ----------
__global__ void k_init0(int* degI, int* cnt, int* cntg, float* svec) {
    int i = blockIdx.x * 256 + threadIdx.x;
    if (i < N) { degI[i] = 1; cnt[i] = 0; }
    if (i < NG) cntg[i] = 0;
    if (i < 128) svec[i] = 0.f;
}

// counts + slot assignment in one pass
__global__ void k_edge_count(const int* __restrict__ ei, int* degI, int* cnt,
                             int* __restrict__ pos_e) {
    int e = blockIdx.x * 256 + threadIdx.x;
    if (e < E) {
        int s = ei[e];
        int d = ei[E + e];
        atomicAdd(&degI[d], 1);                  // in-degree at dst
        pos_e[e] = atomicAdd(&cnt[s], 1);        // out-degree + slot
    }
}

__global__ void k_dinv(const int* __restrict__ degI, float* dinv) {
    int i = blockIdx.x * 256 + threadIdx.x;
    if (i < N) dinv[i] = rsqrtf((float)degI[i]);
}

__global__ void k_scan1(const int* __restrict__ cnt, int* __restrict__ off, int* bsum) {
    __shared__ int buf[256];
    int tid = threadIdx.x;
    int i = blockIdx.x * 256 + tid;
    int v = (i < N) ? cnt[i] : 0;
    buf[tid] = v;
    __syncthreads();
    for (int s = 1; s < 256; s <<= 1) {
        int add = (tid >= s) ? buf[tid - s] : 0;
        __syncthreads();
        buf[tid] += add;
        __syncthreads();
    }
    if (i < N) off[i] = buf[tid] - v;
    if (tid == 255) bsum[blockIdx.x] = buf[255];
}

__global__ void k_scan2(int* bsum, int* off) {
    __shared__ int buf[256];
    int tid = threadIdx.x;
    int v = (tid < SCAN_B) ? bsum[tid] : 0;
    buf[tid] = v;
    __syncthreads();
    for (int s = 1; s < 256; s <<= 1) {
        int add = (tid >= s) ? buf[tid - s] : 0;
        __syncthreads();
        buf[tid] += add;
        __syncthreads();
    }
    if (tid < SCAN_B) bsum[tid] = buf[tid] - v;
    if (tid == 0) off[N] = E;
}

__global__ void k_scan3(int* off, const int* __restrict__ bsum) {
    int i = blockIdx.x * 256 + threadIdx.x;
    if (i < N) off[i] += bsum[blockIdx.x];
}

__global__ void k_csr_fill(const int* __restrict__ ei, const float* __restrict__ dinv,
                           const int* __restrict__ off, const int* __restrict__ pos_e,
                           unsigned long long* __restrict__ meta) {
    int e = blockIdx.x * 256 + threadIdx.x;
    if (e < E) {
        int s = ei[e];
        int d = ei[E + e];
        unsigned long long m =
            ((unsigned long long)__float_as_uint(dinv[s] * dinv[d]) << 32) |
            (unsigned int)d;
        meta[off[s] + pos_e[e]] = m;
    }
}

// ---------- pooling indicator ----------
__global__ void k_cntg(const int* __restrict__ batch, int* cntg) {
    __shared__ int h[NG];
    if (threadIdx.x < NG) h[threadIdx.x] = 0;
    __syncthreads();
    int i = blockIdx.x * 256 + threadIdx.x;
    if (i < N) atomicAdd(&h[batch[i]], 1);
    __syncthreads();
    if (threadIdx.x < NG && h[threadIdx.x]) atomicAdd(&cntg[threadIdx.x], h[threadIdx.x]);
}

// writes the FULL 64-byte row (no memset needed)
__global__ void k_z0(const int* __restrict__ batch, const int* __restrict__ cntg,
                     uint4* Z0) {
    int i = blockIdx.x * 256 + threadIdx.x;
    if (i >= N) return;
    int g = batch[i];
    int c = cntg[g]; if (c < 1) c = 1;
    float v = SCALE / (float)c;
    unsigned int byte = (unsigned int)(__builtin_amdgcn_cvt_pk_fp8_f32(v, v, 0, false) & 0xFF);
    uint4 rows[4];
    #pragma unroll
    for (int q = 0; q < 4; ++q) rows[q] = make_uint4(0u, 0u, 0u, 0u);
    unsigned int* wp = (unsigned int*)rows;
    wp[g >> 2] = byte << (8 * (g & 3));
    #pragma unroll
    for (int q = 0; q < 4; ++q) Z0[(size_t)i * 4 + q] = rows[q];
}

// ---------- hot kernel: one hop of P^T on N x 64 fp8 ----------
// N*8 threads: 4 lanes/node (16B quarter each) x 2 edge-range halves.
// Halves the serial gather chain and doubles resident waves vs N*4.
__device__ __forceinline__ void fma16(float* acc, uint4 g, float w) {
    float f[16];
    unp4(g.x, f); unp4(g.y, f + 4); unp4(g.z, f + 8); unp4(g.w, f + 12);
    #pragma unroll
    for (int k = 0; k < 16; ++k) acc[k] += w * f[k];
}

__global__ __launch_bounds__(256) void k_prop(
        const uint4* __restrict__ zin, uint4* __restrict__ zout,
        const int* __restrict__ off, const unsigned long long* __restrict__ meta,
        const float* __restrict__ dinv) {
    __shared__ float comb[16 * 128];             // k-major: bank-conflict-free
    int t = blockIdx.x * 256 + threadIdx.x;      // N*8 threads
    int node = t >> 3;
    int sub  = (t >> 2) & 1;
    int c    = t & 3;
    bool valid = node < N;

    float acc[16];
    #pragma unroll
    for (int k = 0; k < 16; ++k) acc[k] = 0.f;

    int e = 0, e1 = 0;
    if (valid) {
        int a = off[node], b = off[node + 1];
        int half = (b - a + 1) >> 1;             // sub0 gets ceil
        e  = sub ? a + half : a;
        e1 = sub ? b : a + half;
        if (!sub) {                              // self-loop term on sub0
            float di = dinv[node];
            float ws = di * di;
            uint4 own = zin[(size_t)node * 4 + c];
            float f[16];
            unp4(own.x, f); unp4(own.y, f + 4); unp4(own.z, f + 8); unp4(own.w, f + 12);
            #pragma unroll
            for (int k = 0; k < 16; ++k) acc[k] = ws * f[k];
        }
    }
    for (; e + 3 < e1; e += 4) {                 // 4 gathers in flight
        unsigned long long m0 = __builtin_nontemporal_load(meta + e);
        unsigned long long m1 = __builtin_nontemporal_load(meta + e + 1);
        unsigned long long m2 = __builtin_nontemporal_load(meta + e + 2);
        unsigned long long m3 = __builtin_nontemporal_load(meta + e + 3);
        uint4 g0 = zin[(size_t)(unsigned int)m0 * 4 + c];
        uint4 g1 = zin[(size_t)(unsigned int)m1 * 4 + c];
        uint4 g2 = zin[(size_t)(unsigned int)m2 * 4 + c];
        uint4 g3 = zin[(size_t)(unsigned int)m3 * 4 + c];
        fma16(acc, g0, __uint_as_float((unsigned int)(m0 >> 32)));
        fma16(acc, g1, __uint_as_float((unsigned int)(m1 >> 32)));
        fma16(acc, g2, __uint_as_float((unsigned int)(m2 >> 32)));
        fma16(acc, g3, __uint_as_float((unsigned int)(m3 >> 32)));
    }
    for (; e < e1; ++e) {
        unsigned long long m0 = __builtin_nontemporal_load(meta + e);
        uint4 g0 = zin[(size_t)(unsigned int)m0 * 4 + c];
        fma16(acc, g0, __uint_as_float((unsigned int)(m0 >> 32)));
    }

    int lid = threadIdx.x;
    int pair = (lid >> 3) * 4 + (lid & 3);       // local node*4 + c, 0..127
    if (sub) {
        #pragma unroll
        for (int k = 0; k < 16; ++k) comb[k * 128 + pair] = acc[k];
    }
    __syncthreads();
    if (valid && !sub) {
        #pragma unroll
        for (int k = 0; k < 16; ++k) acc[k] += comb[k * 128 + pair];
        uint4 o;
        o.x = pk4(acc[0],  acc[1],  acc[2],  acc[3]);
        o.y = pk4(acc[4],  acc[5],  acc[6],  acc[7]);
        o.z = pk4(acc[8],  acc[9],  acc[10], acc[11]);
        o.w = pk4(acc[12], acc[13], acc[14], acc[15]);
        zout[(size_t)node * 4 + c] = o;          // stays in L2 for next hop
    }
}

// column sums of fp8 Z -> s[g] * invS
__global__ void k_colsum(const unsigned int* __restrict__ Z, float* s) {
    __shared__ float red[256];
    int g = threadIdx.x & 63, sub = threadIdx.x >> 6;
    int w = g >> 2;
    int word = (g >> 1) & 1;
    int odd  = g & 1;
    float acc = 0.f;
    for (int i = blockIdx.x * 4 + sub; i < N; i += gridDim.x * 4) {
        unsigned int u = Z[(size_t)i * 16 + w];
        floatx2 p = word ? __builtin_amdgcn_cvt_pk_f32_fp8(u, true)
                         : __builtin_amdgcn_cvt_pk_f32_fp8(u, false);
        acc += odd ? p.y : p.x;
    }
    red[threadIdx.x] = acc;
    __syncthreads();
    if (sub == 0)
        atomicAdd(&s[g], (red[g] + red[64 + g] + red[128 + g] + red[192 + g]) * INVSCALE);
}

// partial G = Z15^T X (Z fp8)
__global__ __launch_bounds__(256) void k_gpart(
        const uint4* __restrict__ Z, const float4* __restrict__ X, float* part) {
    __shared__ unsigned int zr[32][16];
    __shared__ float xr[32][128];
    int tid = threadIdx.x;
    int f4 = tid & 31;
    int gs = tid >> 5;
    float4 acc[8];
    #pragma unroll
    for (int k = 0; k < 8; ++k) acc[k] = make_float4(0.f, 0.f, 0.f, 0.f);

    int per = (N + gridDim.x - 1) / gridDim.x;
    int n0 = blockIdx.x * per;
    int n1 = n0 + per; if (n1 > N) n1 = N;

    for (int nb = n0; nb < n1; nb += 32) {
        __syncthreads();
        if (tid < 128) {
            int nn = tid >> 2, q = tid & 3;
            int node = nb + nn;
            uint4 zv = make_uint4(0u, 0u, 0u, 0u);
            if (node < n1) zv = Z[(size_t)node * 4 + q];
            ((uint4*)&zr[nn][0])[q] = zv;
        }
        #pragma unroll
        for (int r = 0; r < 4; ++r) {
            int l = r * 256 + tid;
            int nn = l >> 5, c4 = l & 31;
            int node = nb + nn;
            float4 xv = make_float4(0.f, 0.f, 0.f, 0.f);
            if (node < n1) xv = X[(size_t)node * 32 + c4];
            ((float4*)&xr[nn][0])[c4] = xv;
        }
        __syncthreads();
        for (int nn = 0; nn < 32; ++nn) {
            float4 xv = ((const float4*)&xr[nn][0])[f4];
            unsigned int za = zr[nn][gs * 2], zb = zr[nn][gs * 2 + 1];
            float zf[8];
            unp4(za, zf); unp4(zb, zf + 4);
            #pragma unroll
            for (int k = 0; k < 8; ++k) {
                acc[k].x += zf[k] * xv.x; acc[k].y += zf[k] * xv.y;
                acc[k].z += zf[k] * xv.z; acc[k].w += zf[k] * xv.w;
            }
        }
    }
    float4* dst = (float4*)(part + (size_t)blockIdx.x * 8192);
    #pragma unroll
    for (int k = 0; k < 8; ++k) dst[(gs * 8 + k) * 32 + f4] = acc[k];
}

__global__ void k_greduce(const float4* __restrict__ part, float4* G) {
    __shared__ float4 red[256];
    int tid = threadIdx.x;
    int o4 = blockIdx.x * 16 + (tid & 15);
    int slice = tid >> 4;
    float4 a = make_float4(0.f, 0.f, 0.f, 0.f);
    #pragma unroll 4
    for (int k = 0; k < GP_BLOCKS / 16; ++k) {
        float4 v = part[(size_t)(slice * (GP_BLOCKS / 16) + k) * 2048 + o4];
        a.x += v.x; a.y += v.y; a.z += v.z; a.w += v.w;
    }
    red[tid] = a;
    __syncthreads();
    for (int s = 128; s >= 16; s >>= 1) {
        if (tid < s) {
            float4 b = red[tid + s];
            red[tid].x += b.x; red[tid].y += b.y; red[tid].z += b.z; red[tid].w += b.w;
        }
        __syncthreads();
    }
    if (tid < 16) {
        float4 r = red[tid];
        G[o4] = make_float4(r.x * INVSCALE, r.y * INVSCALE, r.z * INVSCALE, r.w * INVSCALE);
    }
}

// pass1: [W1;b1] (129x160) @ W2 (160x160) -> T1c (129x160)
__global__ void k_pass1(const float* __restrict__ W1, const float* __restrict__ b1,
                        const float* __restrict__ W2, float* T1c) {
    int t = blockIdx.x * 256 + threadIdx.x;
    if (t >= 129 * 160) return;
    int m = t / 160, c = t - m * 160;
    const float* arow = (m < 128) ? (W1 + m * 160) : b1;
    float a = 0.f;
    for (int k = 0; k < 160; ++k) a += arow[k] * W2[k * 160 + c];
    T1c[t] = a;
}

// pass2: [T1; c1a; b2] (130x160) @ W3 (160x128) -> TWc (130x128)
__global__ void k_pass2(const float* __restrict__ T1c, const float* __restrict__ b2,
                        const float* __restrict__ W3, float* TWc) {
    int t = blockIdx.x * 256 + threadIdx.x;
    if (t >= 130 * 128) return;
    int m = t >> 7, c = t & 127;
    const float* arow = (m < 129) ? (T1c + m * 160) : b2;
    float a = 0.f;
    for (int k = 0; k < 160; ++k) a += arow[k] * W3[k * 128 + c];
    TWc[t] = a;
}

// pooled[g,f] = G[g,:]@TWc[0:128,f] + s10[g]*TWc[128,f] + s5[g]*TWc[129,f] + b3[f]
__global__ void k_pooled(const float* __restrict__ G, const float* __restrict__ TWc,
                         const float* __restrict__ b3, const float* __restrict__ svec,
                         float* pooled) {
    int t = blockIdx.x * 256 + threadIdx.x;
    if (t >= NG * OUTC) return;
    int g = t >> 7, f = t & 127;
    float a = b3[f] + svec[64 + g] * TWc[128 * 128 + f] + svec[g] * TWc[129 * 128 + f];
    for (int k = 0; k < 128; ++k) a += G[g * 128 + k] * TWc[k * 128 + f];
    pooled[t] = a;
}

__global__ void k_head(const float* __restrict__ pooled, const float* __restrict__ fcw,
                       const float* __restrict__ fcb, float* out) {
    __shared__ float lg[ODIM];
    int g = blockIdx.x, tid = threadIdx.x;
    if (tid < ODIM) {
        float a = fcb[tid];
        for (int k = 0; k < 128; ++k) a += pooled[g * 128 + k] * fcw[k * ODIM + tid];
        lg[tid] = a;
    }
    __syncthreads();
    if (tid == 0) {
        float mx = lg[0];
        for (int j = 1; j < ODIM; ++j) mx = fmaxf(mx, lg[j]);
        float sum = 0.f;
        for (int j = 0; j < ODIM; ++j) sum += expf(lg[j] - mx);
        float lse = mx + logf(sum);
        for (int j = 0; j < ODIM; ++j) out[g * ODIM + j] = lg[j] - lse;
    }
}

extern "C" void kernel_launch(void* const* d_in, const int* in_sizes, int n_in,
                              void* d_out, int out_size, void* d_ws, size_t ws_size,
                              hipStream_t stream) {
    const float* x    = (const float*)d_in[0];
    const int*   ei   = (const int*)d_in[1];
    const int*   batch= (const int*)d_in[2];
    const float* W1   = (const float*)d_in[3];
    const float* b1   = (const float*)d_in[4];
    const float* W2   = (const float*)d_in[5];
    const float* b2   = (const float*)d_in[6];
    const float* W3   = (const float*)d_in[7];
    const float* b3   = (const float*)d_in[8];
    const float* fcw  = (const float*)d_in[9];
    const float* fcb  = (const float*)d_in[10];
    float* out = (float*)d_out;

    char* p = (char*)d_ws;
    auto alloc = [&](size_t bytes) -> void* {
        void* r = (void*)p;
        p += (bytes + 255) & ~(size_t)255;
        return r;
    };
    int*   degI    = (int*)  alloc((size_t)N * 4);
    float* dinv    = (float*)alloc((size_t)N * 4);
    int*   cnt     = (int*)  alloc((size_t)N * 4);
    int*   off     = (int*)  alloc((size_t)(N + 1) * 4);
    int*   bsum    = (int*)  alloc((size_t)SCAN_B * 4);
    int*   pos_e   = (int*)  alloc((size_t)E * 4);
    unsigned long long* meta = (unsigned long long*)alloc((size_t)E * 8);
    int*   cntg    = (int*)  alloc((size_t)NG * 4);
    float* svec    = (float*)alloc(128 * 4);
    unsigned char* Z0 = (unsigned char*)alloc((size_t)N * 64);
    unsigned char* Z1 = (unsigned char*)alloc((size_t)N * 64);
    float* part    = (float*)alloc((size_t)GP_BLOCKS * 8192 * 4);
    float* G       = (float*)alloc(8192 * 4);
    float* T1c     = (float*)alloc(129 * 160 * 4);
    float* TWc     = (float*)alloc(130 * 128 * 4);
    float* pooled  = (float*)alloc(64 * 128 * 4);

    int nb_n = (N + 255) / 256;
    int nb_e = (E + 255) / 256;
    k_init0<<<nb_n, 256, 0, stream>>>(degI, cnt, cntg, svec);
    k_edge_count<<<nb_e, 256, 0, stream>>>(ei, degI, cnt, pos_e);
    k_dinv<<<nb_n, 256, 0, stream>>>(degI, dinv);
    k_scan1<<<SCAN_B, 256, 0, stream>>>(cnt, off, bsum);
    k_scan2<<<1, 256, 0, stream>>>(bsum, off);
    k_scan3<<<SCAN_B, 256, 0, stream>>>(off, bsum);
    k_csr_fill<<<nb_e, 256, 0, stream>>>(ei, dinv, off, pos_e, meta);
    k_cntg<<<nb_n, 256, 0, stream>>>(batch, cntg);
    k_z0<<<nb_n, 256, 0, stream>>>(batch, cntg, (uint4*)Z0);

    unsigned char* zc = Z0;
    unsigned char* zn = Z1;
    for (int hop = 1; hop <= 15; ++hop) {
        k_prop<<<(N * 8 + 255) / 256, 256, 0, stream>>>(
            (const uint4*)zc, (uint4*)zn, off, meta, dinv);
        unsigned char* t = zc; zc = zn; zn = t;
        if (hop == 5)  k_colsum<<<128, 256, 0, stream>>>((const unsigned int*)zc, svec);
        if (hop == 10) k_colsum<<<128, 256, 0, stream>>>((const unsigned int*)zc, svec + 64);
    }

    k_gpart<<<GP_BLOCKS, 256, 0, stream>>>((const uint4*)zc, (const float4*)x, part);
    k_greduce<<<128, 256, 0, stream>>>((const float4*)part, (float4*)G);

    k_pass1<<<(129 * 160 + 255) / 256, 256, 0, stream>>>(W1, b1, W2, T1c);
    k_pass2<<<(130 * 128 + 255) / 256, 256, 0, stream>>>(T1c, b2, W3, TWc);
    k_pooled<<<32, 256, 0, stream>>>(G, TWc, b3, svec, pooled);
    k_head<<<NG, 64, 0, stream>>>(pooled, fcw, fcb, out);
}